// Round 12
// baseline (338.198 us; speedup 1.0000x reference)
//
#include <hip/hip_runtime.h>

// HIGNN, round 12. Structure identical to R11 (setup -> p1 -> p2_bucket).
// R11 post-mortem: p2/dispatch restructure NEUTRAL -> total ~= p1 + ~30us
// + ~180us fixed (harness/replay). Only p1 (143us) is controllable.
// p1 budget: VALU 56us, DS ~25us (15 ds_read/hh2-iter over KPT=4 edges),
// rest stall. R12: KPT 4->6 (-33% DS/edge, +50% per-wave ILP),
// __launch_bounds__(256,4) to pin 4 waves/SIMD (VGPR<=128).

constexpr int HIDDEN = 64;
constexpr int NB_MAX = 256;      // LDS histogram bins (>= nbuckets)
constexpr int NPB_SHIFT = 9;     // 512 nodes per bucket
constexpr int NPB = 1 << NPB_SHIFT;
constexpr int TILE_F = NPB * 3;  // floats per bucket tile (1536)
constexpr int NET_SLOT = 1024;   // dwords per packed-net slot
constexpr int NET_USED = 640;    // dwords actually staged to LDS

typedef _Float16 h2_t __attribute__((ext_vector_type(2)));

__device__ __forceinline__ unsigned packh2(float a, float b) {
    auto h = __builtin_amdgcn_cvt_pkrtz(a, b);   // __fp16 ext_vector(2)
    return __builtin_bit_cast(unsigned, h);
}
__device__ __forceinline__ float fdot2u(unsigned a, unsigned b, float c) {
    h2_t ha = __builtin_bit_cast(h2_t, a);
    h2_t hb = __builtin_bit_cast(h2_t, b);
#if __has_builtin(__builtin_amdgcn_fdot2)
    return __builtin_amdgcn_fdot2(ha, hb, c, false);
#else
    return fmaf((float)ha.x, (float)hb.x, fmaf((float)ha.y, (float)hb.y, c));
#endif
}

// Packed net slot layout (dword indices within NET_SLOT):
// [0..191]   W1 packed u32. DIN3: [hh] = (W1[0][hh],W1[1][hh]).
//            DIN6: [hh*3+r] = (W1[2r][hh],W1[2r+1][hh]).
// [192..255] b1 f32
// [256..543] W2 packed u32: [256+hh2*9+i] = (W2[2hh2][i],W2[2hh2+1][i])
// [544..552] b2 f32
// [560..623] w1c f32 (DIN3 third-row weight per hh)

// ---------------- Setup: pack 3 nets + zero gcount + pad x ----------------
__global__ __launch_bounds__(256) void setup_kernel(
    const float* __restrict__ x, int n_nodes, float4* __restrict__ x4,
    int* __restrict__ gcount,
    const float* __restrict__ W1_2b, const float* __restrict__ b1_2b,
    const float* __restrict__ W2_2b, const float* __restrict__ b2_2b,
    const float* __restrict__ W1_s,  const float* __restrict__ b1_s,
    const float* __restrict__ W2_s,  const float* __restrict__ b2_s,
    const float* __restrict__ W1_3b, const float* __restrict__ b1_3b,
    const float* __restrict__ W2_3b, const float* __restrict__ b2_3b,
    unsigned* __restrict__ nets)
{
    const int blk = blockIdx.x;
    const int tid = threadIdx.x;
    if (blk < 3) {
        const float *W1, *b1, *W2, *b2; int din;
        if (blk == 0) { W1 = W1_2b; b1 = b1_2b; W2 = W2_2b; b2 = b2_2b; din = 3; }
        else if (blk == 1) { W1 = W1_s; b1 = b1_s; W2 = W2_s; b2 = b2_s; din = 3; }
        else { W1 = W1_3b; b1 = b1_3b; W2 = W2_3b; b2 = b2_3b; din = 6; }
        unsigned* slot = nets + blk * NET_SLOT;
        float* slotf = (float*)slot;
        if (tid < 64) {
            int hh = tid;
            if (din == 3) {
                slot[hh] = packh2(W1[0 * HIDDEN + hh], W1[1 * HIDDEN + hh]);
                slotf[560 + hh] = W1[2 * HIDDEN + hh];
            } else {
                #pragma unroll
                for (int r = 0; r < 3; ++r)
                    slot[hh * 3 + r] =
                        packh2(W1[(2 * r) * HIDDEN + hh], W1[(2 * r + 1) * HIDDEN + hh]);
            }
            slotf[192 + hh] = b1[hh];
        }
        for (int t = tid; t < 288; t += 256) {
            int hh2 = t / 9, i = t - hh2 * 9;
            slot[256 + t] = packh2(W2[(2 * hh2) * 9 + i], W2[(2 * hh2 + 1) * 9 + i]);
        }
        if (tid < 9) slotf[544 + tid] = b2[tid];
        if (blk == 0) gcount[tid] = 0;   // zeroes all NB_MAX bins (256 threads)
    } else {
        int i = (blk - 3) * 256 + tid;
        if (i < n_nodes)
            x4[i] = make_float4(x[3 * i], x[3 * i + 1], x[3 * i + 2], 0.0f);
    }
}

// ---------------- Phase 1: all 3 edge sets, MLP + bucket append ----------------
__global__ __launch_bounds__(256, 4) void p1_edge_kernel(
    const float4* __restrict__ x4,
    const int* __restrict__ e0, long long E0, const float* __restrict__ at0,
    const int* __restrict__ e1, long long E1, const float* __restrict__ at1,
    const int* __restrict__ e2, long long E2, const float* __restrict__ at2,
    int g0, int g1,
    const unsigned* __restrict__ nets,
    float4* __restrict__ records, int* __restrict__ gcount, int cap)
{
    constexpr int BLK = 256;
    constexpr int KPT = 6;

    __shared__ int s_hist[NB_MAX];
    __shared__ int s_base[NB_MAX];
    __shared__ int s_rank[NB_MAX];
    __shared__ unsigned s_net[NET_USED];   // 2.5 KB packed weights

    // block-uniform set select (set index == net index)
    const int blk = blockIdx.x;
    const int* edges; long long E; const float* attr;
    int bidx, nblk, din3;
    const unsigned* wp;
    if (blk < g0)           { edges = e0; E = E0; attr = at0; bidx = blk;          nblk = g0;                 din3 = 1; wp = nets; }
    else if (blk < g0 + g1) { edges = e1; E = E1; attr = at1; bidx = blk - g0;     nblk = g1;                 din3 = 1; wp = nets + NET_SLOT; }
    else                    { edges = e2; E = E2; attr = at2; bidx = blk - g0 - g1; nblk = gridDim.x - g0 - g1; din3 = 0; wp = nets + 2 * NET_SLOT; }

    const int tid = threadIdx.x;
    const long long span = (E + nblk - 1) / nblk;
    const long long lo = (long long)bidx * span;
    const long long hi = (lo + span < E) ? (lo + span) : E;
    if (lo >= E) return;

    for (int i = tid; i < NB_MAX; i += BLK) { s_hist[i] = 0; s_rank[i] = 0; }
    // stage packed net into LDS (covered by the same barrier below)
    for (int i = tid; i < NET_USED; i += BLK) s_net[i] = wp[i];
    __syncthreads();

    const unsigned* w = s_net;
    const float* wf = (const float*)s_net;

    // pass A: histogram of destinations over this block's span
    const long long dstrow = din3 ? E : 2 * E;
    for (long long e = lo + tid; e < hi; e += BLK) {
        int d = edges[dstrow + e];
        atomicAdd(&s_hist[d >> NPB_SHIFT], 1);
    }
    __syncthreads();

    // reserve contiguous per-bucket slots: one global int atomic per nonempty bin
    for (int i = tid; i < NB_MAX; i += BLK) {
        int h = s_hist[i];
        s_base[i] = (h > 0) ? atomicAdd(&gcount[i], h) : 0;
    }
    __syncthreads();

    // pass B: MLP + append, tiles of BLK*KPT edges (6/thread)
    for (long long t0 = lo; t0 < hi; t0 += BLK * KPT) {
        unsigned dp[KPT][3];    // packed fp16 input pairs
        float    d2s[KPT];      // DIN3 third component (fp32)
        float    a[KPT][3];
        int      dst[KPT];
        bool     valid[KPT];

        #pragma unroll
        for (int u = 0; u < KPT; ++u) {
            long long e = t0 + (long long)u * BLK + tid;
            valid[u] = (e < hi);
            long long ee = valid[u] ? e : lo;
            if (din3) {
                int s = edges[ee];
                int t = edges[E + ee];
                dst[u] = t;
                float4 xs = x4[s];
                float4 xt = x4[t];
                dp[u][0] = packh2(xs.x - xt.x, xs.y - xt.y);
                d2s[u]   = xs.z - xt.z;
                dp[u][1] = 0; dp[u][2] = 0;
            } else {
                int j = edges[ee];
                int k = edges[E + ee];
                int i = edges[2 * E + ee];
                dst[u] = i;
                float4 xj = x4[j];
                float4 xk = x4[k];
                float4 xi = x4[i];
                dp[u][0] = packh2(xk.x - xj.x, xk.y - xj.y);
                dp[u][1] = packh2(xk.z - xj.z, xi.x - xk.x);
                dp[u][2] = packh2(xi.y - xk.y, xi.z - xk.z);
                d2s[u] = 0.f;
            }
            #pragma unroll
            for (int c = 0; c < 3; ++c) a[u][c] = attr[3 * ee + c];
        }

        float acc[KPT][9];
        #pragma unroll
        for (int u = 0; u < KPT; ++u)
            #pragma unroll
            for (int i = 0; i < 9; ++i) acc[u][i] = wf[544 + i];  // b2

        if (din3) {
            for (int hh2 = 0; hh2 < HIDDEN / 2; ++hh2) {
                const unsigned wA = w[2 * hh2];
                const unsigned wB = w[2 * hh2 + 1];
                const float wcA = wf[560 + 2 * hh2];
                const float wcB = wf[561 + 2 * hh2];
                const float bbA = wf[192 + 2 * hh2];
                const float bbB = wf[193 + 2 * hh2];
                unsigned w2p[9];
                #pragma unroll
                for (int i = 0; i < 9; ++i) w2p[i] = w[256 + hh2 * 9 + i];
                #pragma unroll
                for (int u = 0; u < KPT; ++u) {
                    float preA = fmaf(d2s[u], wcA, fdot2u(dp[u][0], wA, bbA));
                    float preB = fmaf(d2s[u], wcB, fdot2u(dp[u][0], wB, bbB));
                    unsigned h2 = packh2(fmaxf(preA, 0.f), fmaxf(preB, 0.f));
                    #pragma unroll
                    for (int i = 0; i < 9; ++i)
                        acc[u][i] = fdot2u(h2, w2p[i], acc[u][i]);
                }
            }
        } else {
            for (int hh2 = 0; hh2 < HIDDEN / 2; ++hh2) {
                const unsigned wA0 = w[(2 * hh2) * 3 + 0];
                const unsigned wA1 = w[(2 * hh2) * 3 + 1];
                const unsigned wA2 = w[(2 * hh2) * 3 + 2];
                const unsigned wB0 = w[(2 * hh2 + 1) * 3 + 0];
                const unsigned wB1 = w[(2 * hh2 + 1) * 3 + 1];
                const unsigned wB2 = w[(2 * hh2 + 1) * 3 + 2];
                const float bbA = wf[192 + 2 * hh2];
                const float bbB = wf[193 + 2 * hh2];
                unsigned w2p[9];
                #pragma unroll
                for (int i = 0; i < 9; ++i) w2p[i] = w[256 + hh2 * 9 + i];
                #pragma unroll
                for (int u = 0; u < KPT; ++u) {
                    float preA = fdot2u(dp[u][2], wA2,
                                 fdot2u(dp[u][1], wA1,
                                 fdot2u(dp[u][0], wA0, bbA)));
                    float preB = fdot2u(dp[u][2], wB2,
                                 fdot2u(dp[u][1], wB1,
                                 fdot2u(dp[u][0], wB0, bbB)));
                    unsigned h2 = packh2(fmaxf(preA, 0.f), fmaxf(preB, 0.f));
                    #pragma unroll
                    for (int i = 0; i < 9; ++i)
                        acc[u][i] = fdot2u(h2, w2p[i], acc[u][i]);
                }
            }
        }

        #pragma unroll
        for (int u = 0; u < KPT; ++u) {
            if (!valid[u]) continue;
            float y0 = fmaf(acc[u][0], a[u][0], fmaf(acc[u][1], a[u][1], acc[u][2] * a[u][2]));
            float y1 = fmaf(acc[u][3], a[u][0], fmaf(acc[u][4], a[u][1], acc[u][5] * a[u][2]));
            float y2 = fmaf(acc[u][6], a[u][0], fmaf(acc[u][7], a[u][1], acc[u][8] * a[u][2]));
            int b = dst[u] >> NPB_SHIFT;
            int r = atomicAdd(&s_rank[b], 1);            // LDS, fast
            int slot = s_base[b] + r;
            if (slot < cap)                              // ~12-sigma safety clamp
                records[(size_t)b * cap + slot] =
                    make_float4(y0, y1, y2, __int_as_float(dst[u]));
        }
    }
}

// ---------------- Phase 2: one block per bucket, direct out write ----------------
__global__ __launch_bounds__(1024) void p2_bucket(
    const float4* __restrict__ records, const int* __restrict__ gcount,
    int cap, int n_nodes, float* __restrict__ out)
{
    __shared__ float s_acc[TILE_F];   // 6 KB
    const int b = blockIdx.x;
    const int tid = threadIdx.x;

    for (int i = tid; i < TILE_F; i += 1024) s_acc[i] = 0.0f;
    __syncthreads();

    int cnt = gcount[b];
    if (cnt > cap) cnt = cap;
    const float4* rb = records + (size_t)b * cap;
    for (int i = tid; i < cnt; i += 1024) {
        float4 r = rb[i];
        int loc = __float_as_int(r.w) - (b << NPB_SHIFT);
        atomicAdd(&s_acc[loc * 3 + 0], r.x);
        atomicAdd(&s_acc[loc * 3 + 1], r.y);
        atomicAdd(&s_acc[loc * 3 + 2], r.z);
    }
    __syncthreads();

    const int start = (b << NPB_SHIFT) * 3;
    const int end = min(n_nodes * 3, ((b + 1) << NPB_SHIFT) * 3);
    for (int i = start + tid; i < end; i += 1024)
        out[i] = s_acc[i - start];
}

// ---------------- Fallback (R1): direct device atomics, fp32 ----------------
template <int DIN, int KPT>
__global__ __launch_bounds__(256) void edge_mlp_atomic(
    const float* __restrict__ x,
    const int* __restrict__ edges, long long E,
    const float* __restrict__ attr,
    const float* __restrict__ W1, const float* __restrict__ b1,
    const float* __restrict__ W2, const float* __restrict__ b2,
    float* __restrict__ out)
{
    const int tid = threadIdx.x;
    const long long base = (long long)blockIdx.x * (blockDim.x * KPT) + tid;
    float d[KPT][DIN]; float a[KPT][3]; int dst[KPT]; bool valid[KPT];
    #pragma unroll
    for (int u = 0; u < KPT; ++u) {
        long long e = base + (long long)u * blockDim.x;
        valid[u] = (e < E);
        long long ee = valid[u] ? e : 0;
        if constexpr (DIN == 3) {
            int s = edges[ee]; int t = edges[E + ee]; dst[u] = t;
            #pragma unroll
            for (int c = 0; c < 3; ++c)
                d[u][c] = x[3 * (long long)s + c] - x[3 * (long long)t + c];
        } else {
            int j = edges[ee]; int k = edges[E + ee]; int i = edges[2 * E + ee];
            dst[u] = i;
            #pragma unroll
            for (int c = 0; c < 3; ++c) {
                float xj = x[3 * (long long)j + c];
                float xk = x[3 * (long long)k + c];
                float xi = x[3 * (long long)i + c];
                d[u][c] = xk - xj; d[u][3 + c] = xi - xk;
            }
        }
        #pragma unroll
        for (int c = 0; c < 3; ++c) a[u][c] = attr[3 * ee + c];
    }
    float acc[KPT][9];
    #pragma unroll
    for (int u = 0; u < KPT; ++u)
        #pragma unroll
        for (int i = 0; i < 9; ++i) acc[u][i] = b2[i];
    #pragma unroll 4
    for (int hh = 0; hh < HIDDEN; ++hh) {
        const float bb = b1[hh];
        float w1r[DIN];
        #pragma unroll
        for (int r = 0; r < DIN; ++r) w1r[r] = W1[r * HIDDEN + hh];
        float w2r[9];
        #pragma unroll
        for (int i = 0; i < 9; ++i) w2r[i] = W2[hh * 9 + i];
        #pragma unroll
        for (int u = 0; u < KPT; ++u) {
            float pre = bb;
            #pragma unroll
            for (int r = 0; r < DIN; ++r) pre = fmaf(d[u][r], w1r[r], pre);
            const float h = fmaxf(pre, 0.0f);
            #pragma unroll
            for (int i = 0; i < 9; ++i) acc[u][i] = fmaf(h, w2r[i], acc[u][i]);
        }
    }
    #pragma unroll
    for (int u = 0; u < KPT; ++u) {
        if (!valid[u]) continue;
        float* o = out + 3 * (long long)dst[u];
        #pragma unroll
        for (int i = 0; i < 3; ++i) {
            float y = fmaf(acc[u][3 * i + 0], a[u][0],
                      fmaf(acc[u][3 * i + 1], a[u][1],
                           acc[u][3 * i + 2] * a[u][2]));
            atomicAdd(&o[i], y);
        }
    }
}

extern "C" void kernel_launch(void* const* d_in, const int* in_sizes, int n_in,
                              void* d_out, int out_size, void* d_ws, size_t ws_size,
                              hipStream_t stream)
{
    const float* x  = (const float*)d_in[0];
    const int*   e2 = (const int*)d_in[1];
    const int*   e3 = (const int*)d_in[2];
    const int*   es = (const int*)d_in[3];
    const float* a2 = (const float*)d_in[5];
    const float* a3 = (const float*)d_in[6];
    const float* as = (const float*)d_in[7];
    const float* W1_2b = (const float*)d_in[9];
    const float* b1_2b = (const float*)d_in[10];
    const float* W2_2b = (const float*)d_in[11];
    const float* b2_2b = (const float*)d_in[12];
    const float* W1_3b = (const float*)d_in[13];
    const float* b1_3b = (const float*)d_in[14];
    const float* W2_3b = (const float*)d_in[15];
    const float* b2_3b = (const float*)d_in[16];
    const float* W1_s  = (const float*)d_in[17];
    const float* b1_s  = (const float*)d_in[18];
    const float* W2_s  = (const float*)d_in[19];
    const float* b2_s  = (const float*)d_in[20];

    const long long E2 = in_sizes[1] / 2;
    const long long E3 = in_sizes[2] / 3;
    const long long ES = in_sizes[3] / 2;
    const long long Etot = E2 + E3 + ES;
    const int n_nodes = out_size / 3;
    const int nbuckets = (n_nodes + NPB - 1) >> NPB_SHIFT;

    float* out = (float*)d_out;

    // ws layout: [gcount 1KB][nets 3*4KB][x4][records]
    const size_t off_nets = 1024;
    const size_t off_x4 = off_nets + 3 * NET_SLOT * 4;
    const size_t x4_bytes = (size_t)n_nodes * sizeof(float4);
    const size_t off_rec = (off_x4 + x4_bytes + 255) & ~(size_t)255;

    long long mean_per_bucket = (Etot + nbuckets - 1) / nbuckets;
    long long min_cap = mean_per_bucket + 1600;   // ~12 sigma for binomial load
    long long cap_avail =
        ((long long)ws_size - (long long)off_rec) / ((long long)nbuckets * 16);

    constexpr int SPAN = 3072;    // 2 tiles of 1536 (KPT=6) per block
    int g0 = (int)((E2 + SPAN - 1) / SPAN);
    int g1 = (int)((ES + SPAN - 1) / SPAN);
    int g2g = (int)((E3 + SPAN - 1) / SPAN);

    if (nbuckets <= NB_MAX && cap_avail >= min_cap) {
        long long capL = min_cap + 4096;
        if (capL > cap_avail) capL = cap_avail;
        int cap = (int)capL;
        int* gcount = (int*)d_ws;
        unsigned* nets = (unsigned*)((char*)d_ws + off_nets);
        float4* x4 = (float4*)((char*)d_ws + off_x4);
        float4* records = (float4*)((char*)d_ws + off_rec);

        int nb_pad = (n_nodes + 255) / 256;
        setup_kernel<<<3 + nb_pad, 256, 0, stream>>>(
            x, n_nodes, x4, gcount,
            W1_2b, b1_2b, W2_2b, b2_2b,
            W1_s,  b1_s,  W2_s,  b2_s,
            W1_3b, b1_3b, W2_3b, b2_3b,
            nets);

        p1_edge_kernel<<<g0 + g1 + g2g, 256, 0, stream>>>(
            x4,
            e2, E2, a2,
            es, ES, as,
            e3, E3, a3,
            g0, g1,
            nets, records, gcount, cap);

        p2_bucket<<<nbuckets, 1024, 0, stream>>>(records, gcount, cap, n_nodes, out);
    } else {
        // fallback: direct-atomic fp32 path (correct everywhere)
        hipMemsetAsync(out, 0, (size_t)out_size * sizeof(float), stream);
        constexpr int BLK = 256, KPT = 4;
        const long long per_blk = (long long)BLK * KPT;
        int a2g = (int)((E2 + per_blk - 1) / per_blk);
        int a3g = (int)((E3 + per_blk - 1) / per_blk);
        int asg = (int)((ES + per_blk - 1) / per_blk);
        if (a2g > 0)
            edge_mlp_atomic<3, KPT><<<a2g, BLK, 0, stream>>>(
                x, e2, E2, a2, W1_2b, b1_2b, W2_2b, b2_2b, out);
        if (a3g > 0)
            edge_mlp_atomic<6, KPT><<<a3g, BLK, 0, stream>>>(
                x, e3, E3, a3, W1_3b, b1_3b, W2_3b, b2_3b, out);
        if (asg > 0)
            edge_mlp_atomic<3, KPT><<<asg, BLK, 0, stream>>>(
                x, es, ES, as, W1_s, b1_s, W2_s, b2_s, out);
    }
}

// Round 13
// 318.296 us; speedup vs baseline: 1.0625x; 1.0625x over previous
//
#include <hip/hip_runtime.h>

// HIGNN, round 13. R12 (KPT=6) REVERTED: compiler spilled (FETCH/WRITE +8MB
// scratch signature), p1 143->160us. Base = R11 (KPT=4, 143us).
// R13 change: pass-B streaming loads vectorized. Edge->lane mapping switched
// from strided to 4-consecutive-edges/thread so the 20 scalar dword loads per
// tile (edge rows + attr) become 5 dwordx4 loads (1KB/wave/instr). Random x4
// gathers unchanged. Span rounded to 1024 for 16B alignment; scalar fallback
// for ragged tails / unaligned E.

constexpr int HIDDEN = 64;
constexpr int NB_MAX = 256;      // LDS histogram bins (>= nbuckets)
constexpr int NPB_SHIFT = 9;     // 512 nodes per bucket
constexpr int NPB = 1 << NPB_SHIFT;
constexpr int TILE_F = NPB * 3;  // floats per bucket tile (1536)
constexpr int NET_SLOT = 1024;   // dwords per packed-net slot
constexpr int NET_USED = 640;    // dwords actually staged to LDS

typedef _Float16 h2_t __attribute__((ext_vector_type(2)));

__device__ __forceinline__ unsigned packh2(float a, float b) {
    auto h = __builtin_amdgcn_cvt_pkrtz(a, b);   // __fp16 ext_vector(2)
    return __builtin_bit_cast(unsigned, h);
}
__device__ __forceinline__ float fdot2u(unsigned a, unsigned b, float c) {
    h2_t ha = __builtin_bit_cast(h2_t, a);
    h2_t hb = __builtin_bit_cast(h2_t, b);
#if __has_builtin(__builtin_amdgcn_fdot2)
    return __builtin_amdgcn_fdot2(ha, hb, c, false);
#else
    return fmaf((float)ha.x, (float)hb.x, fmaf((float)ha.y, (float)hb.y, c));
#endif
}

// Packed net slot layout (dword indices within NET_SLOT):
// [0..191]   W1 packed u32. DIN3: [hh] = (W1[0][hh],W1[1][hh]).
//            DIN6: [hh*3+r] = (W1[2r][hh],W1[2r+1][hh]).
// [192..255] b1 f32
// [256..543] W2 packed u32: [256+hh2*9+i] = (W2[2hh2][i],W2[2hh2+1][i])
// [544..552] b2 f32
// [560..623] w1c f32 (DIN3 third-row weight per hh)

// ---------------- Setup: pack 3 nets + zero gcount + pad x ----------------
__global__ __launch_bounds__(256) void setup_kernel(
    const float* __restrict__ x, int n_nodes, float4* __restrict__ x4,
    int* __restrict__ gcount,
    const float* __restrict__ W1_2b, const float* __restrict__ b1_2b,
    const float* __restrict__ W2_2b, const float* __restrict__ b2_2b,
    const float* __restrict__ W1_s,  const float* __restrict__ b1_s,
    const float* __restrict__ W2_s,  const float* __restrict__ b2_s,
    const float* __restrict__ W1_3b, const float* __restrict__ b1_3b,
    const float* __restrict__ W2_3b, const float* __restrict__ b2_3b,
    unsigned* __restrict__ nets)
{
    const int blk = blockIdx.x;
    const int tid = threadIdx.x;
    if (blk < 3) {
        const float *W1, *b1, *W2, *b2; int din;
        if (blk == 0) { W1 = W1_2b; b1 = b1_2b; W2 = W2_2b; b2 = b2_2b; din = 3; }
        else if (blk == 1) { W1 = W1_s; b1 = b1_s; W2 = W2_s; b2 = b2_s; din = 3; }
        else { W1 = W1_3b; b1 = b1_3b; W2 = W2_3b; b2 = b2_3b; din = 6; }
        unsigned* slot = nets + blk * NET_SLOT;
        float* slotf = (float*)slot;
        if (tid < 64) {
            int hh = tid;
            if (din == 3) {
                slot[hh] = packh2(W1[0 * HIDDEN + hh], W1[1 * HIDDEN + hh]);
                slotf[560 + hh] = W1[2 * HIDDEN + hh];
            } else {
                #pragma unroll
                for (int r = 0; r < 3; ++r)
                    slot[hh * 3 + r] =
                        packh2(W1[(2 * r) * HIDDEN + hh], W1[(2 * r + 1) * HIDDEN + hh]);
            }
            slotf[192 + hh] = b1[hh];
        }
        for (int t = tid; t < 288; t += 256) {
            int hh2 = t / 9, i = t - hh2 * 9;
            slot[256 + t] = packh2(W2[(2 * hh2) * 9 + i], W2[(2 * hh2 + 1) * 9 + i]);
        }
        if (tid < 9) slotf[544 + tid] = b2[tid];
        if (blk == 0) gcount[tid] = 0;   // zeroes all NB_MAX bins (256 threads)
    } else {
        int i = (blk - 3) * 256 + tid;
        if (i < n_nodes)
            x4[i] = make_float4(x[3 * i], x[3 * i + 1], x[3 * i + 2], 0.0f);
    }
}

// ---------------- Phase 1: all 3 edge sets, MLP + bucket append ----------------
__global__ __launch_bounds__(256) void p1_edge_kernel(
    const float4* __restrict__ x4,
    const int* __restrict__ e0, long long E0, const float* __restrict__ at0,
    const int* __restrict__ e1, long long E1, const float* __restrict__ at1,
    const int* __restrict__ e2, long long E2, const float* __restrict__ at2,
    int g0, int g1,
    const unsigned* __restrict__ nets,
    float4* __restrict__ records, int* __restrict__ gcount, int cap)
{
    constexpr int BLK = 256;
    constexpr int KPT = 4;

    __shared__ int s_hist[NB_MAX];
    __shared__ int s_base[NB_MAX];
    __shared__ int s_rank[NB_MAX];
    __shared__ unsigned s_net[NET_USED];   // 2.5 KB packed weights

    // block-uniform set select (set index == net index)
    const int blk = blockIdx.x;
    const int* edges; long long E; const float* attr;
    int bidx, nblk, din3;
    const unsigned* wp;
    if (blk < g0)           { edges = e0; E = E0; attr = at0; bidx = blk;          nblk = g0;                 din3 = 1; wp = nets; }
    else if (blk < g0 + g1) { edges = e1; E = E1; attr = at1; bidx = blk - g0;     nblk = g1;                 din3 = 1; wp = nets + NET_SLOT; }
    else                    { edges = e2; E = E2; attr = at2; bidx = blk - g0 - g1; nblk = gridDim.x - g0 - g1; din3 = 0; wp = nets + 2 * NET_SLOT; }

    const int tid = threadIdx.x;
    // span rounded to 1024 so every tile base (and thread base) is 4-aligned
    long long span = (E + nblk - 1) / nblk;
    span = (span + 1023) & ~1023LL;
    const long long lo = (long long)bidx * span;
    const long long hi = (lo + span < E) ? (lo + span) : E;
    if (lo >= E) return;

    const bool e_aligned = ((E & 3) == 0);

    for (int i = tid; i < NB_MAX; i += BLK) { s_hist[i] = 0; s_rank[i] = 0; }
    // stage packed net into LDS (covered by the same barrier below)
    for (int i = tid; i < NET_USED; i += BLK) s_net[i] = wp[i];
    __syncthreads();

    const unsigned* w = s_net;
    const float* wf = (const float*)s_net;

    // pass A: histogram of destinations over this block's span
    const long long dstrow = din3 ? E : 2 * E;
    for (long long e = lo + tid; e < hi; e += BLK) {
        int d = edges[dstrow + e];
        atomicAdd(&s_hist[d >> NPB_SHIFT], 1);
    }
    __syncthreads();

    // reserve contiguous per-bucket slots: one global int atomic per nonempty bin
    for (int i = tid; i < NB_MAX; i += BLK) {
        int h = s_hist[i];
        s_base[i] = (h > 0) ? atomicAdd(&gcount[i], h) : 0;
    }
    __syncthreads();

    // pass B: MLP + append. KPT=4 CONSECUTIVE edges per thread ->
    // edge-row and attr loads become dwordx4 (1KB/wave/instr).
    for (long long t0 = lo; t0 < hi; t0 += BLK * KPT) {
        const long long be = t0 + (long long)tid * KPT;   // 4-aligned

        unsigned dp[KPT][3];
        float    d2s[KPT];
        float    a[KPT][3];
        int      dst[KPT];
        bool     valid[KPT];
        int      i0[KPT], i1[KPT], i2[KPT];

        const bool full = e_aligned && (be + KPT <= hi);
        if (full) {
            int4 r0 = *(const int4*)(edges + be);
            int4 r1 = *(const int4*)(edges + E + be);
            i0[0] = r0.x; i0[1] = r0.y; i0[2] = r0.z; i0[3] = r0.w;
            i1[0] = r1.x; i1[1] = r1.y; i1[2] = r1.z; i1[3] = r1.w;
            if (!din3) {
                int4 r2 = *(const int4*)(edges + 2 * E + be);
                i2[0] = r2.x; i2[1] = r2.y; i2[2] = r2.z; i2[3] = r2.w;
            }
            float4 a0 = *(const float4*)(attr + 3 * be);
            float4 a1 = *(const float4*)(attr + 3 * be + 4);
            float4 a2 = *(const float4*)(attr + 3 * be + 8);
            a[0][0] = a0.x; a[0][1] = a0.y; a[0][2] = a0.z;
            a[1][0] = a0.w; a[1][1] = a1.x; a[1][2] = a1.y;
            a[2][0] = a1.z; a[2][1] = a1.w; a[2][2] = a2.x;
            a[3][0] = a2.y; a[3][1] = a2.z; a[3][2] = a2.w;
            #pragma unroll
            for (int u = 0; u < KPT; ++u) valid[u] = true;
        } else {
            #pragma unroll
            for (int u = 0; u < KPT; ++u) {
                long long e = be + u;
                valid[u] = (e < hi);
                long long ee = valid[u] ? e : lo;
                i0[u] = edges[ee];
                i1[u] = edges[E + ee];
                if (!din3) i2[u] = edges[2 * E + ee];
                #pragma unroll
                for (int c = 0; c < 3; ++c) a[u][c] = attr[3 * ee + c];
            }
        }

        if (be >= hi) continue;   // fully-empty tile for this thread

        #pragma unroll
        for (int u = 0; u < KPT; ++u) {
            if (din3) {
                dst[u] = i1[u];
                float4 xs = x4[i0[u]];
                float4 xt = x4[i1[u]];
                dp[u][0] = packh2(xs.x - xt.x, xs.y - xt.y);
                d2s[u]   = xs.z - xt.z;
                dp[u][1] = 0; dp[u][2] = 0;
            } else {
                dst[u] = i2[u];
                float4 xj = x4[i0[u]];
                float4 xk = x4[i1[u]];
                float4 xi = x4[i2[u]];
                dp[u][0] = packh2(xk.x - xj.x, xk.y - xj.y);
                dp[u][1] = packh2(xk.z - xj.z, xi.x - xk.x);
                dp[u][2] = packh2(xi.y - xk.y, xi.z - xk.z);
                d2s[u] = 0.f;
            }
        }

        float acc[KPT][9];
        #pragma unroll
        for (int u = 0; u < KPT; ++u)
            #pragma unroll
            for (int i = 0; i < 9; ++i) acc[u][i] = wf[544 + i];  // b2

        if (din3) {
            #pragma unroll 2
            for (int hh2 = 0; hh2 < HIDDEN / 2; ++hh2) {
                const unsigned wA = w[2 * hh2];
                const unsigned wB = w[2 * hh2 + 1];
                const float wcA = wf[560 + 2 * hh2];
                const float wcB = wf[561 + 2 * hh2];
                const float bbA = wf[192 + 2 * hh2];
                const float bbB = wf[193 + 2 * hh2];
                unsigned w2p[9];
                #pragma unroll
                for (int i = 0; i < 9; ++i) w2p[i] = w[256 + hh2 * 9 + i];
                #pragma unroll
                for (int u = 0; u < KPT; ++u) {
                    float preA = fmaf(d2s[u], wcA, fdot2u(dp[u][0], wA, bbA));
                    float preB = fmaf(d2s[u], wcB, fdot2u(dp[u][0], wB, bbB));
                    unsigned h2 = packh2(fmaxf(preA, 0.f), fmaxf(preB, 0.f));
                    #pragma unroll
                    for (int i = 0; i < 9; ++i)
                        acc[u][i] = fdot2u(h2, w2p[i], acc[u][i]);
                }
            }
        } else {
            #pragma unroll 2
            for (int hh2 = 0; hh2 < HIDDEN / 2; ++hh2) {
                const unsigned wA0 = w[(2 * hh2) * 3 + 0];
                const unsigned wA1 = w[(2 * hh2) * 3 + 1];
                const unsigned wA2 = w[(2 * hh2) * 3 + 2];
                const unsigned wB0 = w[(2 * hh2 + 1) * 3 + 0];
                const unsigned wB1 = w[(2 * hh2 + 1) * 3 + 1];
                const unsigned wB2 = w[(2 * hh2 + 1) * 3 + 2];
                const float bbA = wf[192 + 2 * hh2];
                const float bbB = wf[193 + 2 * hh2];
                unsigned w2p[9];
                #pragma unroll
                for (int i = 0; i < 9; ++i) w2p[i] = w[256 + hh2 * 9 + i];
                #pragma unroll
                for (int u = 0; u < KPT; ++u) {
                    float preA = fdot2u(dp[u][2], wA2,
                                 fdot2u(dp[u][1], wA1,
                                 fdot2u(dp[u][0], wA0, bbA)));
                    float preB = fdot2u(dp[u][2], wB2,
                                 fdot2u(dp[u][1], wB1,
                                 fdot2u(dp[u][0], wB0, bbB)));
                    unsigned h2 = packh2(fmaxf(preA, 0.f), fmaxf(preB, 0.f));
                    #pragma unroll
                    for (int i = 0; i < 9; ++i)
                        acc[u][i] = fdot2u(h2, w2p[i], acc[u][i]);
                }
            }
        }

        #pragma unroll
        for (int u = 0; u < KPT; ++u) {
            if (!valid[u]) continue;
            float y0 = fmaf(acc[u][0], a[u][0], fmaf(acc[u][1], a[u][1], acc[u][2] * a[u][2]));
            float y1 = fmaf(acc[u][3], a[u][0], fmaf(acc[u][4], a[u][1], acc[u][5] * a[u][2]));
            float y2 = fmaf(acc[u][6], a[u][0], fmaf(acc[u][7], a[u][1], acc[u][8] * a[u][2]));
            int b = dst[u] >> NPB_SHIFT;
            int r = atomicAdd(&s_rank[b], 1);            // LDS, fast
            int slot = s_base[b] + r;
            if (slot < cap)                              // ~12-sigma safety clamp
                records[(size_t)b * cap + slot] =
                    make_float4(y0, y1, y2, __int_as_float(dst[u]));
        }
    }
}

// ---------------- Phase 2: one block per bucket, direct out write ----------------
__global__ __launch_bounds__(1024) void p2_bucket(
    const float4* __restrict__ records, const int* __restrict__ gcount,
    int cap, int n_nodes, float* __restrict__ out)
{
    __shared__ float s_acc[TILE_F];   // 6 KB
    const int b = blockIdx.x;
    const int tid = threadIdx.x;

    for (int i = tid; i < TILE_F; i += 1024) s_acc[i] = 0.0f;
    __syncthreads();

    int cnt = gcount[b];
    if (cnt > cap) cnt = cap;
    const float4* rb = records + (size_t)b * cap;
    for (int i = tid; i < cnt; i += 1024) {
        float4 r = rb[i];
        int loc = __float_as_int(r.w) - (b << NPB_SHIFT);
        atomicAdd(&s_acc[loc * 3 + 0], r.x);
        atomicAdd(&s_acc[loc * 3 + 1], r.y);
        atomicAdd(&s_acc[loc * 3 + 2], r.z);
    }
    __syncthreads();

    const int start = (b << NPB_SHIFT) * 3;
    const int end = min(n_nodes * 3, ((b + 1) << NPB_SHIFT) * 3);
    for (int i = start + tid; i < end; i += 1024)
        out[i] = s_acc[i - start];
}

// ---------------- Fallback (R1): direct device atomics, fp32 ----------------
template <int DIN, int KPT>
__global__ __launch_bounds__(256) void edge_mlp_atomic(
    const float* __restrict__ x,
    const int* __restrict__ edges, long long E,
    const float* __restrict__ attr,
    const float* __restrict__ W1, const float* __restrict__ b1,
    const float* __restrict__ W2, const float* __restrict__ b2,
    float* __restrict__ out)
{
    const int tid = threadIdx.x;
    const long long base = (long long)blockIdx.x * (blockDim.x * KPT) + tid;
    float d[KPT][DIN]; float a[KPT][3]; int dst[KPT]; bool valid[KPT];
    #pragma unroll
    for (int u = 0; u < KPT; ++u) {
        long long e = base + (long long)u * blockDim.x;
        valid[u] = (e < E);
        long long ee = valid[u] ? e : 0;
        if constexpr (DIN == 3) {
            int s = edges[ee]; int t = edges[E + ee]; dst[u] = t;
            #pragma unroll
            for (int c = 0; c < 3; ++c)
                d[u][c] = x[3 * (long long)s + c] - x[3 * (long long)t + c];
        } else {
            int j = edges[ee]; int k = edges[E + ee]; int i = edges[2 * E + ee];
            dst[u] = i;
            #pragma unroll
            for (int c = 0; c < 3; ++c) {
                float xj = x[3 * (long long)j + c];
                float xk = x[3 * (long long)k + c];
                float xi = x[3 * (long long)i + c];
                d[u][c] = xk - xj; d[u][3 + c] = xi - xk;
            }
        }
        #pragma unroll
        for (int c = 0; c < 3; ++c) a[u][c] = attr[3 * ee + c];
    }
    float acc[KPT][9];
    #pragma unroll
    for (int u = 0; u < KPT; ++u)
        #pragma unroll
        for (int i = 0; i < 9; ++i) acc[u][i] = b2[i];
    #pragma unroll 4
    for (int hh = 0; hh < HIDDEN; ++hh) {
        const float bb = b1[hh];
        float w1r[DIN];
        #pragma unroll
        for (int r = 0; r < DIN; ++r) w1r[r] = W1[r * HIDDEN + hh];
        float w2r[9];
        #pragma unroll
        for (int i = 0; i < 9; ++i) w2r[i] = W2[hh * 9 + i];
        #pragma unroll
        for (int u = 0; u < KPT; ++u) {
            float pre = bb;
            #pragma unroll
            for (int r = 0; r < DIN; ++r) pre = fmaf(d[u][r], w1r[r], pre);
            const float h = fmaxf(pre, 0.0f);
            #pragma unroll
            for (int i = 0; i < 9; ++i) acc[u][i] = fmaf(h, w2r[i], acc[u][i]);
        }
    }
    #pragma unroll
    for (int u = 0; u < KPT; ++u) {
        if (!valid[u]) continue;
        float* o = out + 3 * (long long)dst[u];
        #pragma unroll
        for (int i = 0; i < 3; ++i) {
            float y = fmaf(acc[u][3 * i + 0], a[u][0],
                      fmaf(acc[u][3 * i + 1], a[u][1],
                           acc[u][3 * i + 2] * a[u][2]));
            atomicAdd(&o[i], y);
        }
    }
}

extern "C" void kernel_launch(void* const* d_in, const int* in_sizes, int n_in,
                              void* d_out, int out_size, void* d_ws, size_t ws_size,
                              hipStream_t stream)
{
    const float* x  = (const float*)d_in[0];
    const int*   e2 = (const int*)d_in[1];
    const int*   e3 = (const int*)d_in[2];
    const int*   es = (const int*)d_in[3];
    const float* a2 = (const float*)d_in[5];
    const float* a3 = (const float*)d_in[6];
    const float* as = (const float*)d_in[7];
    const float* W1_2b = (const float*)d_in[9];
    const float* b1_2b = (const float*)d_in[10];
    const float* W2_2b = (const float*)d_in[11];
    const float* b2_2b = (const float*)d_in[12];
    const float* W1_3b = (const float*)d_in[13];
    const float* b1_3b = (const float*)d_in[14];
    const float* W2_3b = (const float*)d_in[15];
    const float* b2_3b = (const float*)d_in[16];
    const float* W1_s  = (const float*)d_in[17];
    const float* b1_s  = (const float*)d_in[18];
    const float* W2_s  = (const float*)d_in[19];
    const float* b2_s  = (const float*)d_in[20];

    const long long E2 = in_sizes[1] / 2;
    const long long E3 = in_sizes[2] / 3;
    const long long ES = in_sizes[3] / 2;
    const long long Etot = E2 + E3 + ES;
    const int n_nodes = out_size / 3;
    const int nbuckets = (n_nodes + NPB - 1) >> NPB_SHIFT;

    float* out = (float*)d_out;

    // ws layout: [gcount 1KB][nets 3*4KB][x4][records]
    const size_t off_nets = 1024;
    const size_t off_x4 = off_nets + 3 * NET_SLOT * 4;
    const size_t x4_bytes = (size_t)n_nodes * sizeof(float4);
    const size_t off_rec = (off_x4 + x4_bytes + 255) & ~(size_t)255;

    long long mean_per_bucket = (Etot + nbuckets - 1) / nbuckets;
    long long min_cap = mean_per_bucket + 1600;   // ~12 sigma for binomial load
    long long cap_avail =
        ((long long)ws_size - (long long)off_rec) / ((long long)nbuckets * 16);

    constexpr int SPAN = 2048;    // 2 tiles of 1024 per block
    int g0 = (int)((E2 + SPAN - 1) / SPAN);
    int g1 = (int)((ES + SPAN - 1) / SPAN);
    int g2g = (int)((E3 + SPAN - 1) / SPAN);

    if (nbuckets <= NB_MAX && cap_avail >= min_cap) {
        long long capL = min_cap + 4096;
        if (capL > cap_avail) capL = cap_avail;
        int cap = (int)capL;
        int* gcount = (int*)d_ws;
        unsigned* nets = (unsigned*)((char*)d_ws + off_nets);
        float4* x4 = (float4*)((char*)d_ws + off_x4);
        float4* records = (float4*)((char*)d_ws + off_rec);

        int nb_pad = (n_nodes + 255) / 256;
        setup_kernel<<<3 + nb_pad, 256, 0, stream>>>(
            x, n_nodes, x4, gcount,
            W1_2b, b1_2b, W2_2b, b2_2b,
            W1_s,  b1_s,  W2_s,  b2_s,
            W1_3b, b1_3b, W2_3b, b2_3b,
            nets);

        p1_edge_kernel<<<g0 + g1 + g2g, 256, 0, stream>>>(
            x4,
            e2, E2, a2,
            es, ES, as,
            e3, E3, a3,
            g0, g1,
            nets, records, gcount, cap);

        p2_bucket<<<nbuckets, 1024, 0, stream>>>(records, gcount, cap, n_nodes, out);
    } else {
        // fallback: direct-atomic fp32 path (correct everywhere)
        hipMemsetAsync(out, 0, (size_t)out_size * sizeof(float), stream);
        constexpr int BLK = 256, KPT = 4;
        const long long per_blk = (long long)BLK * KPT;
        int a2g = (int)((E2 + per_blk - 1) / per_blk);
        int a3g = (int)((E3 + per_blk - 1) / per_blk);
        int asg = (int)((ES + per_blk - 1) / per_blk);
        if (a2g > 0)
            edge_mlp_atomic<3, KPT><<<a2g, BLK, 0, stream>>>(
                x, e2, E2, a2, W1_2b, b1_2b, W2_2b, b2_2b, out);
        if (a3g > 0)
            edge_mlp_atomic<6, KPT><<<a3g, BLK, 0, stream>>>(
                x, e3, E3, a3, W1_3b, b1_3b, W2_3b, b2_3b, out);
        if (asg > 0)
            edge_mlp_atomic<3, KPT><<<asg, BLK, 0, stream>>>(
                x, es, ES, as, W1_s, b1_s, W2_s, b2_s, out);
    }
}

// Round 14
// 315.563 us; speedup vs baseline: 1.0717x; 1.0087x over previous
//
#include <hip/hip_runtime.h>

// HIGNN, round 14 = R13 (318us best) + pass-A histogram loads vectorized
// (same consecutive-4/int4 treatment R13 applied to pass B; pass A was the
// last scalar-strided streaming reader). Everything else frozen.

constexpr int HIDDEN = 64;
constexpr int NB_MAX = 256;      // LDS histogram bins (>= nbuckets)
constexpr int NPB_SHIFT = 9;     // 512 nodes per bucket
constexpr int NPB = 1 << NPB_SHIFT;
constexpr int TILE_F = NPB * 3;  // floats per bucket tile (1536)
constexpr int NET_SLOT = 1024;   // dwords per packed-net slot
constexpr int NET_USED = 640;    // dwords actually staged to LDS

typedef _Float16 h2_t __attribute__((ext_vector_type(2)));

__device__ __forceinline__ unsigned packh2(float a, float b) {
    auto h = __builtin_amdgcn_cvt_pkrtz(a, b);   // __fp16 ext_vector(2)
    return __builtin_bit_cast(unsigned, h);
}
__device__ __forceinline__ float fdot2u(unsigned a, unsigned b, float c) {
    h2_t ha = __builtin_bit_cast(h2_t, a);
    h2_t hb = __builtin_bit_cast(h2_t, b);
#if __has_builtin(__builtin_amdgcn_fdot2)
    return __builtin_amdgcn_fdot2(ha, hb, c, false);
#else
    return fmaf((float)ha.x, (float)hb.x, fmaf((float)ha.y, (float)hb.y, c));
#endif
}

// Packed net slot layout (dword indices within NET_SLOT):
// [0..191]   W1 packed u32. DIN3: [hh] = (W1[0][hh],W1[1][hh]).
//            DIN6: [hh*3+r] = (W1[2r][hh],W1[2r+1][hh]).
// [192..255] b1 f32
// [256..543] W2 packed u32: [256+hh2*9+i] = (W2[2hh2][i],W2[2hh2+1][i])
// [544..552] b2 f32
// [560..623] w1c f32 (DIN3 third-row weight per hh)

// ---------------- Setup: pack 3 nets + zero gcount + pad x ----------------
__global__ __launch_bounds__(256) void setup_kernel(
    const float* __restrict__ x, int n_nodes, float4* __restrict__ x4,
    int* __restrict__ gcount,
    const float* __restrict__ W1_2b, const float* __restrict__ b1_2b,
    const float* __restrict__ W2_2b, const float* __restrict__ b2_2b,
    const float* __restrict__ W1_s,  const float* __restrict__ b1_s,
    const float* __restrict__ W2_s,  const float* __restrict__ b2_s,
    const float* __restrict__ W1_3b, const float* __restrict__ b1_3b,
    const float* __restrict__ W2_3b, const float* __restrict__ b2_3b,
    unsigned* __restrict__ nets)
{
    const int blk = blockIdx.x;
    const int tid = threadIdx.x;
    if (blk < 3) {
        const float *W1, *b1, *W2, *b2; int din;
        if (blk == 0) { W1 = W1_2b; b1 = b1_2b; W2 = W2_2b; b2 = b2_2b; din = 3; }
        else if (blk == 1) { W1 = W1_s; b1 = b1_s; W2 = W2_s; b2 = b2_s; din = 3; }
        else { W1 = W1_3b; b1 = b1_3b; W2 = W2_3b; b2 = b2_3b; din = 6; }
        unsigned* slot = nets + blk * NET_SLOT;
        float* slotf = (float*)slot;
        if (tid < 64) {
            int hh = tid;
            if (din == 3) {
                slot[hh] = packh2(W1[0 * HIDDEN + hh], W1[1 * HIDDEN + hh]);
                slotf[560 + hh] = W1[2 * HIDDEN + hh];
            } else {
                #pragma unroll
                for (int r = 0; r < 3; ++r)
                    slot[hh * 3 + r] =
                        packh2(W1[(2 * r) * HIDDEN + hh], W1[(2 * r + 1) * HIDDEN + hh]);
            }
            slotf[192 + hh] = b1[hh];
        }
        for (int t = tid; t < 288; t += 256) {
            int hh2 = t / 9, i = t - hh2 * 9;
            slot[256 + t] = packh2(W2[(2 * hh2) * 9 + i], W2[(2 * hh2 + 1) * 9 + i]);
        }
        if (tid < 9) slotf[544 + tid] = b2[tid];
        if (blk == 0) gcount[tid] = 0;   // zeroes all NB_MAX bins (256 threads)
    } else {
        int i = (blk - 3) * 256 + tid;
        if (i < n_nodes)
            x4[i] = make_float4(x[3 * i], x[3 * i + 1], x[3 * i + 2], 0.0f);
    }
}

// ---------------- Phase 1: all 3 edge sets, MLP + bucket append ----------------
__global__ __launch_bounds__(256) void p1_edge_kernel(
    const float4* __restrict__ x4,
    const int* __restrict__ e0, long long E0, const float* __restrict__ at0,
    const int* __restrict__ e1, long long E1, const float* __restrict__ at1,
    const int* __restrict__ e2, long long E2, const float* __restrict__ at2,
    int g0, int g1,
    const unsigned* __restrict__ nets,
    float4* __restrict__ records, int* __restrict__ gcount, int cap)
{
    constexpr int BLK = 256;
    constexpr int KPT = 4;

    __shared__ int s_hist[NB_MAX];
    __shared__ int s_base[NB_MAX];
    __shared__ int s_rank[NB_MAX];
    __shared__ unsigned s_net[NET_USED];   // 2.5 KB packed weights

    // block-uniform set select (set index == net index)
    const int blk = blockIdx.x;
    const int* edges; long long E; const float* attr;
    int bidx, nblk, din3;
    const unsigned* wp;
    if (blk < g0)           { edges = e0; E = E0; attr = at0; bidx = blk;          nblk = g0;                 din3 = 1; wp = nets; }
    else if (blk < g0 + g1) { edges = e1; E = E1; attr = at1; bidx = blk - g0;     nblk = g1;                 din3 = 1; wp = nets + NET_SLOT; }
    else                    { edges = e2; E = E2; attr = at2; bidx = blk - g0 - g1; nblk = gridDim.x - g0 - g1; din3 = 0; wp = nets + 2 * NET_SLOT; }

    const int tid = threadIdx.x;
    // span rounded to 1024 so every tile base (and thread base) is 4-aligned
    long long span = (E + nblk - 1) / nblk;
    span = (span + 1023) & ~1023LL;
    const long long lo = (long long)bidx * span;
    const long long hi = (lo + span < E) ? (lo + span) : E;
    if (lo >= E) return;

    const bool e_aligned = ((E & 3) == 0);

    for (int i = tid; i < NB_MAX; i += BLK) { s_hist[i] = 0; s_rank[i] = 0; }
    // stage packed net into LDS (covered by the same barrier below)
    for (int i = tid; i < NET_USED; i += BLK) s_net[i] = wp[i];
    __syncthreads();

    const unsigned* w = s_net;
    const float* wf = (const float*)s_net;

    // pass A: histogram of destinations, vectorized (4 consecutive per thread)
    const long long dstrow = din3 ? E : 2 * E;
    for (long long t0 = lo; t0 < hi; t0 += BLK * KPT) {
        const long long be = t0 + (long long)tid * KPT;   // 4-aligned
        if (be >= hi) continue;
        if (e_aligned && be + KPT <= hi) {
            int4 r = *(const int4*)(edges + dstrow + be);
            atomicAdd(&s_hist[r.x >> NPB_SHIFT], 1);
            atomicAdd(&s_hist[r.y >> NPB_SHIFT], 1);
            atomicAdd(&s_hist[r.z >> NPB_SHIFT], 1);
            atomicAdd(&s_hist[r.w >> NPB_SHIFT], 1);
        } else {
            #pragma unroll
            for (int u = 0; u < KPT; ++u) {
                long long e = be + u;
                if (e < hi)
                    atomicAdd(&s_hist[edges[dstrow + e] >> NPB_SHIFT], 1);
            }
        }
    }
    __syncthreads();

    // reserve contiguous per-bucket slots: one global int atomic per nonempty bin
    for (int i = tid; i < NB_MAX; i += BLK) {
        int h = s_hist[i];
        s_base[i] = (h > 0) ? atomicAdd(&gcount[i], h) : 0;
    }
    __syncthreads();

    // pass B: MLP + append. KPT=4 CONSECUTIVE edges per thread ->
    // edge-row and attr loads are dwordx4 (1KB/wave/instr).
    for (long long t0 = lo; t0 < hi; t0 += BLK * KPT) {
        const long long be = t0 + (long long)tid * KPT;   // 4-aligned

        unsigned dp[KPT][3];
        float    d2s[KPT];
        float    a[KPT][3];
        int      dst[KPT];
        bool     valid[KPT];
        int      i0[KPT], i1[KPT], i2[KPT];

        const bool full = e_aligned && (be + KPT <= hi);
        if (full) {
            int4 r0 = *(const int4*)(edges + be);
            int4 r1 = *(const int4*)(edges + E + be);
            i0[0] = r0.x; i0[1] = r0.y; i0[2] = r0.z; i0[3] = r0.w;
            i1[0] = r1.x; i1[1] = r1.y; i1[2] = r1.z; i1[3] = r1.w;
            if (!din3) {
                int4 r2 = *(const int4*)(edges + 2 * E + be);
                i2[0] = r2.x; i2[1] = r2.y; i2[2] = r2.z; i2[3] = r2.w;
            }
            float4 a0 = *(const float4*)(attr + 3 * be);
            float4 a1 = *(const float4*)(attr + 3 * be + 4);
            float4 a2 = *(const float4*)(attr + 3 * be + 8);
            a[0][0] = a0.x; a[0][1] = a0.y; a[0][2] = a0.z;
            a[1][0] = a0.w; a[1][1] = a1.x; a[1][2] = a1.y;
            a[2][0] = a1.z; a[2][1] = a1.w; a[2][2] = a2.x;
            a[3][0] = a2.y; a[3][1] = a2.z; a[3][2] = a2.w;
            #pragma unroll
            for (int u = 0; u < KPT; ++u) valid[u] = true;
        } else {
            #pragma unroll
            for (int u = 0; u < KPT; ++u) {
                long long e = be + u;
                valid[u] = (e < hi);
                long long ee = valid[u] ? e : lo;
                i0[u] = edges[ee];
                i1[u] = edges[E + ee];
                if (!din3) i2[u] = edges[2 * E + ee];
                #pragma unroll
                for (int c = 0; c < 3; ++c) a[u][c] = attr[3 * ee + c];
            }
        }

        if (be >= hi) continue;   // fully-empty tile for this thread

        #pragma unroll
        for (int u = 0; u < KPT; ++u) {
            if (din3) {
                dst[u] = i1[u];
                float4 xs = x4[i0[u]];
                float4 xt = x4[i1[u]];
                dp[u][0] = packh2(xs.x - xt.x, xs.y - xt.y);
                d2s[u]   = xs.z - xt.z;
                dp[u][1] = 0; dp[u][2] = 0;
            } else {
                dst[u] = i2[u];
                float4 xj = x4[i0[u]];
                float4 xk = x4[i1[u]];
                float4 xi = x4[i2[u]];
                dp[u][0] = packh2(xk.x - xj.x, xk.y - xj.y);
                dp[u][1] = packh2(xk.z - xj.z, xi.x - xk.x);
                dp[u][2] = packh2(xi.y - xk.y, xi.z - xk.z);
                d2s[u] = 0.f;
            }
        }

        float acc[KPT][9];
        #pragma unroll
        for (int u = 0; u < KPT; ++u)
            #pragma unroll
            for (int i = 0; i < 9; ++i) acc[u][i] = wf[544 + i];  // b2

        if (din3) {
            #pragma unroll 2
            for (int hh2 = 0; hh2 < HIDDEN / 2; ++hh2) {
                const unsigned wA = w[2 * hh2];
                const unsigned wB = w[2 * hh2 + 1];
                const float wcA = wf[560 + 2 * hh2];
                const float wcB = wf[561 + 2 * hh2];
                const float bbA = wf[192 + 2 * hh2];
                const float bbB = wf[193 + 2 * hh2];
                unsigned w2p[9];
                #pragma unroll
                for (int i = 0; i < 9; ++i) w2p[i] = w[256 + hh2 * 9 + i];
                #pragma unroll
                for (int u = 0; u < KPT; ++u) {
                    float preA = fmaf(d2s[u], wcA, fdot2u(dp[u][0], wA, bbA));
                    float preB = fmaf(d2s[u], wcB, fdot2u(dp[u][0], wB, bbB));
                    unsigned h2 = packh2(fmaxf(preA, 0.f), fmaxf(preB, 0.f));
                    #pragma unroll
                    for (int i = 0; i < 9; ++i)
                        acc[u][i] = fdot2u(h2, w2p[i], acc[u][i]);
                }
            }
        } else {
            #pragma unroll 2
            for (int hh2 = 0; hh2 < HIDDEN / 2; ++hh2) {
                const unsigned wA0 = w[(2 * hh2) * 3 + 0];
                const unsigned wA1 = w[(2 * hh2) * 3 + 1];
                const unsigned wA2 = w[(2 * hh2) * 3 + 2];
                const unsigned wB0 = w[(2 * hh2 + 1) * 3 + 0];
                const unsigned wB1 = w[(2 * hh2 + 1) * 3 + 1];
                const unsigned wB2 = w[(2 * hh2 + 1) * 3 + 2];
                const float bbA = wf[192 + 2 * hh2];
                const float bbB = wf[193 + 2 * hh2];
                unsigned w2p[9];
                #pragma unroll
                for (int i = 0; i < 9; ++i) w2p[i] = w[256 + hh2 * 9 + i];
                #pragma unroll
                for (int u = 0; u < KPT; ++u) {
                    float preA = fdot2u(dp[u][2], wA2,
                                 fdot2u(dp[u][1], wA1,
                                 fdot2u(dp[u][0], wA0, bbA)));
                    float preB = fdot2u(dp[u][2], wB2,
                                 fdot2u(dp[u][1], wB1,
                                 fdot2u(dp[u][0], wB0, bbB)));
                    unsigned h2 = packh2(fmaxf(preA, 0.f), fmaxf(preB, 0.f));
                    #pragma unroll
                    for (int i = 0; i < 9; ++i)
                        acc[u][i] = fdot2u(h2, w2p[i], acc[u][i]);
                }
            }
        }

        #pragma unroll
        for (int u = 0; u < KPT; ++u) {
            if (!valid[u]) continue;
            float y0 = fmaf(acc[u][0], a[u][0], fmaf(acc[u][1], a[u][1], acc[u][2] * a[u][2]));
            float y1 = fmaf(acc[u][3], a[u][0], fmaf(acc[u][4], a[u][1], acc[u][5] * a[u][2]));
            float y2 = fmaf(acc[u][6], a[u][0], fmaf(acc[u][7], a[u][1], acc[u][8] * a[u][2]));
            int b = dst[u] >> NPB_SHIFT;
            int r = atomicAdd(&s_rank[b], 1);            // LDS, fast
            int slot = s_base[b] + r;
            if (slot < cap)                              // ~12-sigma safety clamp
                records[(size_t)b * cap + slot] =
                    make_float4(y0, y1, y2, __int_as_float(dst[u]));
        }
    }
}

// ---------------- Phase 2: one block per bucket, direct out write ----------------
__global__ __launch_bounds__(1024) void p2_bucket(
    const float4* __restrict__ records, const int* __restrict__ gcount,
    int cap, int n_nodes, float* __restrict__ out)
{
    __shared__ float s_acc[TILE_F];   // 6 KB
    const int b = blockIdx.x;
    const int tid = threadIdx.x;

    for (int i = tid; i < TILE_F; i += 1024) s_acc[i] = 0.0f;
    __syncthreads();

    int cnt = gcount[b];
    if (cnt > cap) cnt = cap;
    const float4* rb = records + (size_t)b * cap;
    for (int i = tid; i < cnt; i += 1024) {
        float4 r = rb[i];
        int loc = __float_as_int(r.w) - (b << NPB_SHIFT);
        atomicAdd(&s_acc[loc * 3 + 0], r.x);
        atomicAdd(&s_acc[loc * 3 + 1], r.y);
        atomicAdd(&s_acc[loc * 3 + 2], r.z);
    }
    __syncthreads();

    const int start = (b << NPB_SHIFT) * 3;
    const int end = min(n_nodes * 3, ((b + 1) << NPB_SHIFT) * 3);
    for (int i = start + tid; i < end; i += 1024)
        out[i] = s_acc[i - start];
}

// ---------------- Fallback (R1): direct device atomics, fp32 ----------------
template <int DIN, int KPT>
__global__ __launch_bounds__(256) void edge_mlp_atomic(
    const float* __restrict__ x,
    const int* __restrict__ edges, long long E,
    const float* __restrict__ attr,
    const float* __restrict__ W1, const float* __restrict__ b1,
    const float* __restrict__ W2, const float* __restrict__ b2,
    float* __restrict__ out)
{
    const int tid = threadIdx.x;
    const long long base = (long long)blockIdx.x * (blockDim.x * KPT) + tid;
    float d[KPT][DIN]; float a[KPT][3]; int dst[KPT]; bool valid[KPT];
    #pragma unroll
    for (int u = 0; u < KPT; ++u) {
        long long e = base + (long long)u * blockDim.x;
        valid[u] = (e < E);
        long long ee = valid[u] ? e : 0;
        if constexpr (DIN == 3) {
            int s = edges[ee]; int t = edges[E + ee]; dst[u] = t;
            #pragma unroll
            for (int c = 0; c < 3; ++c)
                d[u][c] = x[3 * (long long)s + c] - x[3 * (long long)t + c];
        } else {
            int j = edges[ee]; int k = edges[E + ee]; int i = edges[2 * E + ee];
            dst[u] = i;
            #pragma unroll
            for (int c = 0; c < 3; ++c) {
                float xj = x[3 * (long long)j + c];
                float xk = x[3 * (long long)k + c];
                float xi = x[3 * (long long)i + c];
                d[u][c] = xk - xj; d[u][3 + c] = xi - xk;
            }
        }
        #pragma unroll
        for (int c = 0; c < 3; ++c) a[u][c] = attr[3 * ee + c];
    }
    float acc[KPT][9];
    #pragma unroll
    for (int u = 0; u < KPT; ++u)
        #pragma unroll
        for (int i = 0; i < 9; ++i) acc[u][i] = b2[i];
    #pragma unroll 4
    for (int hh = 0; hh < HIDDEN; ++hh) {
        const float bb = b1[hh];
        float w1r[DIN];
        #pragma unroll
        for (int r = 0; r < DIN; ++r) w1r[r] = W1[r * HIDDEN + hh];
        float w2r[9];
        #pragma unroll
        for (int i = 0; i < 9; ++i) w2r[i] = W2[hh * 9 + i];
        #pragma unroll
        for (int u = 0; u < KPT; ++u) {
            float pre = bb;
            #pragma unroll
            for (int r = 0; r < DIN; ++r) pre = fmaf(d[u][r], w1r[r], pre);
            const float h = fmaxf(pre, 0.0f);
            #pragma unroll
            for (int i = 0; i < 9; ++i) acc[u][i] = fmaf(h, w2r[i], acc[u][i]);
        }
    }
    #pragma unroll
    for (int u = 0; u < KPT; ++u) {
        if (!valid[u]) continue;
        float* o = out + 3 * (long long)dst[u];
        #pragma unroll
        for (int i = 0; i < 3; ++i) {
            float y = fmaf(acc[u][3 * i + 0], a[u][0],
                      fmaf(acc[u][3 * i + 1], a[u][1],
                           acc[u][3 * i + 2] * a[u][2]));
            atomicAdd(&o[i], y);
        }
    }
}

extern "C" void kernel_launch(void* const* d_in, const int* in_sizes, int n_in,
                              void* d_out, int out_size, void* d_ws, size_t ws_size,
                              hipStream_t stream)
{
    const float* x  = (const float*)d_in[0];
    const int*   e2 = (const int*)d_in[1];
    const int*   e3 = (const int*)d_in[2];
    const int*   es = (const int*)d_in[3];
    const float* a2 = (const float*)d_in[5];
    const float* a3 = (const float*)d_in[6];
    const float* as = (const float*)d_in[7];
    const float* W1_2b = (const float*)d_in[9];
    const float* b1_2b = (const float*)d_in[10];
    const float* W2_2b = (const float*)d_in[11];
    const float* b2_2b = (const float*)d_in[12];
    const float* W1_3b = (const float*)d_in[13];
    const float* b1_3b = (const float*)d_in[14];
    const float* W2_3b = (const float*)d_in[15];
    const float* b2_3b = (const float*)d_in[16];
    const float* W1_s  = (const float*)d_in[17];
    const float* b1_s  = (const float*)d_in[18];
    const float* W2_s  = (const float*)d_in[19];
    const float* b2_s  = (const float*)d_in[20];

    const long long E2 = in_sizes[1] / 2;
    const long long E3 = in_sizes[2] / 3;
    const long long ES = in_sizes[3] / 2;
    const long long Etot = E2 + E3 + ES;
    const int n_nodes = out_size / 3;
    const int nbuckets = (n_nodes + NPB - 1) >> NPB_SHIFT;

    float* out = (float*)d_out;

    // ws layout: [gcount 1KB][nets 3*4KB][x4][records]
    const size_t off_nets = 1024;
    const size_t off_x4 = off_nets + 3 * NET_SLOT * 4;
    const size_t x4_bytes = (size_t)n_nodes * sizeof(float4);
    const size_t off_rec = (off_x4 + x4_bytes + 255) & ~(size_t)255;

    long long mean_per_bucket = (Etot + nbuckets - 1) / nbuckets;
    long long min_cap = mean_per_bucket + 1600;   // ~12 sigma for binomial load
    long long cap_avail =
        ((long long)ws_size - (long long)off_rec) / ((long long)nbuckets * 16);

    constexpr int SPAN = 2048;    // 2 tiles of 1024 per block
    int g0 = (int)((E2 + SPAN - 1) / SPAN);
    int g1 = (int)((ES + SPAN - 1) / SPAN);
    int g2g = (int)((E3 + SPAN - 1) / SPAN);

    if (nbuckets <= NB_MAX && cap_avail >= min_cap) {
        long long capL = min_cap + 4096;
        if (capL > cap_avail) capL = cap_avail;
        int cap = (int)capL;
        int* gcount = (int*)d_ws;
        unsigned* nets = (unsigned*)((char*)d_ws + off_nets);
        float4* x4 = (float4*)((char*)d_ws + off_x4);
        float4* records = (float4*)((char*)d_ws + off_rec);

        int nb_pad = (n_nodes + 255) / 256;
        setup_kernel<<<3 + nb_pad, 256, 0, stream>>>(
            x, n_nodes, x4, gcount,
            W1_2b, b1_2b, W2_2b, b2_2b,
            W1_s,  b1_s,  W2_s,  b2_s,
            W1_3b, b1_3b, W2_3b, b2_3b,
            nets);

        p1_edge_kernel<<<g0 + g1 + g2g, 256, 0, stream>>>(
            x4,
            e2, E2, a2,
            es, ES, as,
            e3, E3, a3,
            g0, g1,
            nets, records, gcount, cap);

        p2_bucket<<<nbuckets, 1024, 0, stream>>>(records, gcount, cap, n_nodes, out);
    } else {
        // fallback: direct-atomic fp32 path (correct everywhere)
        hipMemsetAsync(out, 0, (size_t)out_size * sizeof(float), stream);
        constexpr int BLK = 256, KPT = 4;
        const long long per_blk = (long long)BLK * KPT;
        int a2g = (int)((E2 + per_blk - 1) / per_blk);
        int a3g = (int)((E3 + per_blk - 1) / per_blk);
        int asg = (int)((ES + per_blk - 1) / per_blk);
        if (a2g > 0)
            edge_mlp_atomic<3, KPT><<<a2g, BLK, 0, stream>>>(
                x, e2, E2, a2, W1_2b, b1_2b, W2_2b, b2_2b, out);
        if (a3g > 0)
            edge_mlp_atomic<6, KPT><<<a3g, BLK, 0, stream>>>(
                x, e3, E3, a3, W1_3b, b1_3b, W2_3b, b2_3b, out);
        if (asg > 0)
            edge_mlp_atomic<3, KPT><<<asg, BLK, 0, stream>>>(
                x, es, ES, as, W1_s, b1_s, W2_s, b2_s, out);
    }
}